// Round 9
// baseline (77.338 us; speedup 1.0000x reference)
//
#include <hip/hip_runtime.h>
#include <hip/hip_fp16.h>

#define LATENT 128
#define DQK    32
#define BB     4
#define NN     16384
#define KK     64
#define TOTAL_EDGES (BB * NN * KK)   // 4,194,304
#define TOTAL_NODES (BB * NN)        // 65,536
#define PADF   132                   // f32 LDS row stride (floats)
#define EPT    2                     // edges per thread (edge kernel)

// ---------------------------------------------------------------------------
// i8 dot helper: 4 x i8 pairs -> i32 accumulate
// ---------------------------------------------------------------------------
__device__ __forceinline__ int dot4i8(int a, int b, int c) {
#if __has_builtin(__builtin_amdgcn_sdot4)
    return __builtin_amdgcn_sdot4(a, b, c, false);
#else
    c += ((a << 24) >> 24) * ((b << 24) >> 24);
    c += ((a << 16) >> 24) * ((b << 16) >> 24);
    c += ((a <<  8) >> 24) * ((b <<  8) >> 24);
    c += (a >> 24) * (b >> 24);
    return c;
#endif
}

// ---------------------------------------------------------------------------
// Kernel 1: proj + int8 row quantization (r8 version, ~12-14 us).
// ---------------------------------------------------------------------------
__global__ __launch_bounds__(256, 2) void proj_kernel(
    const float* __restrict__ features,  // [B*N, 128]
    const float* __restrict__ Wk,        // [32, 128]
    const float* __restrict__ bk,        // [32]
    const float* __restrict__ Wq,        // [32, 128]
    const float* __restrict__ bq,        // [32]
    signed char* __restrict__ ks8,       // [B*N, 32] i8
    signed char* __restrict__ qs8,       // [B*N, 32] i8
    __half* __restrict__ sk,             // [B*N] f16 row scales
    __half* __restrict__ sq)
{
    __shared__ float sf[64 * PADF];
    __shared__ float sw[64 * PADF];      // rows 0..31 = Wk, 32..63 = Wq
    __shared__ float sb[64];

    const int t = threadIdx.x;
    const int node0 = blockIdx.x * 64;

    #pragma unroll
    for (int j = 0; j < 8; ++j) {
        int idx = t + j * 256;
        int r = idx >> 5;
        int c = idx & 31;
        const float4* src = (r < 32) ? (const float4*)Wk : (const float4*)Wq;
        float4 v = src[(size_t)(r & 31) * 32 + c];
        *(float4*)&sw[r * PADF + c * 4] = v;
    }
    if (t < 64) sb[t] = (t < 32) ? bk[t] : bq[t - 32];

    #pragma unroll
    for (int j = 0; j < 8; ++j) {
        int idx = t + j * 256;
        int r = idx >> 5;
        int c = idx & 31;
        float4 v = ((const float4*)(features + (size_t)(node0 + r) * LATENT))[c];
        *(float4*)&sf[r * PADF + c * 4] = v;
    }
    __syncthreads();

    const int tx = t & 15;               // dims tx + 16u
    const int ty = t >> 4;               // nodes ty*4 + i

    float acc[4][4];
    #pragma unroll
    for (int i = 0; i < 4; ++i)
        #pragma unroll
        for (int u = 0; u < 4; ++u) acc[i][u] = 0.f;

    #pragma unroll 4
    for (int kk = 0; kk < 32; ++kk) {
        float4 a[4], b[4];
        #pragma unroll
        for (int i = 0; i < 4; ++i)
            a[i] = *(const float4*)&sf[(ty * 4 + i) * PADF + kk * 4];
        #pragma unroll
        for (int u = 0; u < 4; ++u)
            b[u] = *(const float4*)&sw[(tx + 16 * u) * PADF + kk * 4];
        #pragma unroll
        for (int i = 0; i < 4; ++i)
            #pragma unroll
            for (int u = 0; u < 4; ++u)
                acc[i][u] += a[i].x * b[u].x + a[i].y * b[u].y
                           + a[i].z * b[u].z + a[i].w * b[u].w;
    }

    // ---- quantizing epilogue ----
    float vk0[4], vk1[4], vq0[4], vq1[4], mk[4], mq[4];
    #pragma unroll
    for (int i = 0; i < 4; ++i) {
        vk0[i] = acc[i][0] + sb[tx];
        vk1[i] = acc[i][1] + sb[tx + 16];
        vq0[i] = acc[i][2] + sb[tx + 32];
        vq1[i] = acc[i][3] + sb[tx + 48];
        mk[i] = fmaxf(fabsf(vk0[i]), fabsf(vk1[i]));
        mq[i] = fmaxf(fabsf(vq0[i]), fabsf(vq1[i]));
    }
    #pragma unroll
    for (int mask = 1; mask < 16; mask <<= 1) {
        #pragma unroll
        for (int i = 0; i < 4; ++i) {
            mk[i] = fmaxf(mk[i], __shfl_xor(mk[i], mask));
            mq[i] = fmaxf(mq[i], __shfl_xor(mq[i], mask));
        }
    }
    #pragma unroll
    for (int i = 0; i < 4; ++i) {
        const int node = node0 + ty * 4 + i;
        const float invk = (mk[i] > 0.f) ? 127.f / mk[i] : 0.f;
        const float invq = (mq[i] > 0.f) ? 127.f / mq[i] : 0.f;
        signed char* kr = ks8 + (size_t)node * 32;
        signed char* qr = qs8 + (size_t)node * 32;
        kr[tx]      = (signed char)__float2int_rn(vk0[i] * invk);
        kr[tx + 16] = (signed char)__float2int_rn(vk1[i] * invk);
        qr[tx]      = (signed char)__float2int_rn(vq0[i] * invq);
        qr[tx + 16] = (signed char)__float2int_rn(vq1[i] * invq);
        if (tx == 0) {
            sk[node] = __float2half(mk[i] * (1.f / 127.f));
            sq[node] = __float2half(mq[i] * (1.f / 127.f));
        }
    }
}

// ---------------------------------------------------------------------------
// Kernel 2: i8 edge dots — occupancy-shaped.
// 1024-thread blocks: the fixed 64KB scale-LDS is amortized by 16 waves,
// so 2 blocks/CU = 32 waves (100%) vs r8's 16. EPT=2 keeps VGPR <= 64
// (8 live gather uint4 = 32 regs). 4 divergent 16B lane-addresses per edge.
// ---------------------------------------------------------------------------
__global__ __launch_bounds__(1024, 8) void edge_kernel(
    const int* __restrict__ xidx,        // indices row 1, [B*N*K]
    const int* __restrict__ yidx,        // indices row 2
    const signed char* __restrict__ ks8, // [B*N, 32] i8
    const signed char* __restrict__ qs8,
    const __half* __restrict__ sk,       // [B*N] f16
    const __half* __restrict__ sq,
    float* __restrict__ out)             // [B*N*K]
{
    __shared__ __half ssk[NN];           // 32 KB
    __shared__ __half ssq[NN];           // 32 KB

    const int t = threadIdx.x;
    const int b = blockIdx.x >> 9;       // 512 blocks per batch

    // Stage scale tables (coalesced uint4: 2048 per table, 2/thread each)
    const uint4* gk = (const uint4*)(sk + (size_t)b * NN);
    const uint4* gq = (const uint4*)(sq + (size_t)b * NN);
    uint4* lk = (uint4*)ssk;
    uint4* lq = (uint4*)ssq;
    #pragma unroll
    for (int j = 0; j < 2; ++j) {
        lk[t + j * 1024] = gk[t + j * 1024];
        lq[t + j * 1024] = gq[t + j * 1024];
    }
    __syncthreads();

    const int base_e = (blockIdx.x & 511) * (1024 * EPT);  // within batch
    const int gbase  = b << 20;                            // batch edge offset
    const size_t nodebase = (size_t)b << 14;               // b * NN

    // Phase 1: coalesced index loads
    int xs[EPT], ys[EPT];
    #pragma unroll
    for (int m = 0; m < EPT; ++m) {
        const int e = base_e + m * 1024 + t;
        xs[m] = xidx[gbase + e];
        ys[m] = yidx[gbase + e];
    }
    __builtin_amdgcn_sched_barrier(0);

    // Phase 2: all divergent gathers in flight (4 per edge, 8 total)
    uint4 kv0[EPT], kv1[EPT], qv0[EPT], qv1[EPT];
    const uint4* k4 = (const uint4*)ks8;
    const uint4* q4 = (const uint4*)qs8;
    #pragma unroll
    for (int m = 0; m < EPT; ++m) {
        const size_t xo = (nodebase + (size_t)xs[m]) << 1;  // uint4 units
        const size_t yo = (nodebase + (size_t)ys[m]) << 1;
        kv0[m] = k4[xo];
        kv1[m] = k4[xo + 1];
        qv0[m] = q4[yo];
        qv1[m] = q4[yo + 1];
    }
    __builtin_amdgcn_sched_barrier(0);

    // Phase 3: lane-local i8 dot + LDS scale lookup + coalesced store
    #pragma unroll
    for (int m = 0; m < EPT; ++m) {
        int d = 0;
        d = dot4i8((int)kv0[m].x, (int)qv0[m].x, d);
        d = dot4i8((int)kv0[m].y, (int)qv0[m].y, d);
        d = dot4i8((int)kv0[m].z, (int)qv0[m].z, d);
        d = dot4i8((int)kv0[m].w, (int)qv0[m].w, d);
        d = dot4i8((int)kv1[m].x, (int)qv1[m].x, d);
        d = dot4i8((int)kv1[m].y, (int)qv1[m].y, d);
        d = dot4i8((int)kv1[m].z, (int)qv1[m].z, d);
        d = dot4i8((int)kv1[m].w, (int)qv1[m].w, d);
        const float skx = __half2float(ssk[xs[m]]);
        const float sqy = __half2float(ssq[ys[m]]);
        const int e = base_e + m * 1024 + t;
        out[gbase + e] = (float)d * skx * sqy * 0.17677669529663687f;
    }
}

// ---------------------------------------------------------------------------
extern "C" void kernel_launch(void* const* d_in, const int* in_sizes, int n_in,
                              void* d_out, int out_size, void* d_ws, size_t ws_size,
                              hipStream_t stream) {
    // Input order: indices, img, features, Wk, bk, Wq, bq
    const int*   indices  = (const int*)d_in[0];
    const float* features = (const float*)d_in[2];
    const float* Wk       = (const float*)d_in[3];
    const float* bk       = (const float*)d_in[4];
    const float* Wq       = (const float*)d_in[5];
    const float* bq       = (const float*)d_in[6];
    float* out = (float*)d_out;

    // ws layout: ks8 (2MB) | qs8 (2MB) | sk (128KB f16) | sq (128KB f16)
    signed char* ks8 = (signed char*)d_ws;
    signed char* qs8 = ks8 + (size_t)TOTAL_NODES * 32;
    __half* sk = (__half*)(qs8 + (size_t)TOTAL_NODES * 32);
    __half* sq = sk + TOTAL_NODES;

    const int* xidx = indices + (size_t)1 * TOTAL_EDGES;  // row 1 -> keys
    const int* yidx = indices + (size_t)2 * TOTAL_EDGES;  // row 2 -> queries

    proj_kernel<<<TOTAL_NODES / 64, 256, 0, stream>>>(
        features, Wk, bk, Wq, bq, ks8, qs8, sk, sq);
    // 512 blocks/batch x 4 batches; 1024 threads x EPT(2) edges = 2048 edges/block
    edge_kernel<<<BB * 512, 1024, 0, stream>>>(xidx, yidx, ks8, qs8, sk, sq, out);
}